// Round 6
// baseline (152.989 us; speedup 1.0000x reference)
//
#include <hip/hip_runtime.h>
#include <hip/hip_bf16.h>

#define BB 32
#define CC 128
#define HH 96
#define WW 96
#define BN_EPS 1e-5f

typedef __attribute__((ext_vector_type(8))) short bf16x8_t;
typedef __attribute__((ext_vector_type(4))) float f32x4_t;
typedef __attribute__((ext_vector_type(4), aligned(4))) float f32x4u_t;

// ---------------------------------------------------------------------------
// Prep: W fp32 -> bf16, k-permuted for mfma_f32_16x16x32_bf16 split-k frags
//   storage cidx = kc*32 + g*8 + j  <->  actual c = kc*32 + g*4 + (j&3) + 16*(j>>2)
// Also folds BN to inv/bias.   (unchanged — verified)
// ---------------------------------------------------------------------------
__global__ __launch_bounds__(256)
void prep_kernel(const float* __restrict__ pw,
                 const float* __restrict__ g, const float* __restrict__ b,
                 const float* __restrict__ m, const float* __restrict__ v,
                 unsigned short* __restrict__ wper,
                 float* __restrict__ inv, float* __restrict__ bias)
{
    int t = blockIdx.x * 256 + threadIdx.x;
    if (t < CC * CC) {
        int o = t >> 7, cidx = t & 127;
        int kc = cidx >> 5, r = cidx & 31, gg = r >> 3, j = r & 7;
        int c = kc * 32 + gg * 4 + (j & 3) + 16 * (j >> 2);
        __hip_bfloat16 h = __float2bfloat16(pw[o * CC + c]);
        wper[o * CC + cidx] = *reinterpret_cast<unsigned short*>(&h);
    }
    if (t < CC) {
        float iv = g[t] * rsqrtf(v[t] + BN_EPS);
        inv[t] = iv;
        bias[t] = b[t] - m[t] * iv;
    }
}

// ---------------------------------------------------------------------------
// Main R6: one block = batch bb x (8w x 8h) tile, all 128 channels. 16KB LDS.
//   Stage 1: thread = (4-wide w quad, ONE storage channel). 10 rows x 6 floats
//     loaded as ONE burst (30 VMEM), pinned in VGPRs via asm keep-alive so the
//     compiler cannot re-sink them (R4/R5 lesson: it sank to 60-68 VGPR and
//     serialized the chain). ~85 live regs < 102 cap from launch_bounds(256,5)
//     -> 5 blocks/CU (20 waves) for latency overlap.
//   Stage 2: bf16 MFMA 128o x 64p x 128c + BN + ReLU. Formulas identical to
//     the R3-verified layout (rows now 64). LDS byte-swizzle ^((p&7)<<4).
//   Grid 4608 flat, chunked XCD swizzle (T1, bijective: 4608 % 8 == 0).
// ---------------------------------------------------------------------------
__global__ __launch_bounds__(256, 5)
void fused_main(const float* __restrict__ x, const float* __restrict__ kk,
                const unsigned short* __restrict__ wper,
                const float* __restrict__ invp, const float* __restrict__ biasp,
                float* __restrict__ out)
{
    __shared__ __align__(16) unsigned char xnb[64 * 256];   // 16 KB

    const int tid = threadIdx.x;

    // chunked XCD swizzle (4608 = 8 x 576)
    const unsigned wg  = blockIdx.x;
    const unsigned nid = (wg & 7u) * 576u + (wg >> 3);
    const int bx = nid % 12u;
    const int by = (nid / 12u) % 12u;
    const int bb = nid / 144u;
    const int w0 = bx * 8;
    const int h0 = by * 8;

    // ---------------- stage 1: depthwise (1 channel / thread) ----------------
    {
        const int quad = tid & 1;            // two 4-wide quads cover 8 w
        const int s    = tid >> 1;           // storage channel 0..127
        const int kc = s >> 5, rr = s & 31, gg = rr >> 3, jj = rr & 7;
        const int cA = kc * 32 + gg * 4 + (jj & 3) + 16 * (jj >> 2);

        const int gw = w0 + quad * 4;
        const bool l_edge = (gw == 0);
        const bool r_edge = (gw + 4 >= WW);

        const float* plane = x + (size_t)(bb * CC + cA) * (HH * WW);

        // 9 weights (4B-aligned vector loads)
        float kw[9];
        {
            const float* kp = kk + (size_t)(bb * CC + cA) * 9;
            f32x4u_t q0 = *(const f32x4u_t*)(kp + 0);
            f32x4u_t q1 = *(const f32x4u_t*)(kp + 4);
            float e8 = kp[8];
            kw[0]=q0.x; kw[1]=q0.y; kw[2]=q0.z; kw[3]=q0.w;
            kw[4]=q1.x; kw[5]=q1.y; kw[6]=q1.z; kw[7]=q1.w;
            kw[8]=e8;
        }

        // upfront burst: 10 rows x 6 floats, all independent VMEM
        float xd[10][6];
        #pragma unroll
        for (int r = 0; r < 10; ++r) {
            const int row = h0 - 1 + r;
            const bool valid = (row >= 0) && (row < HH);     // block-uniform
            const int rrow = row < 0 ? 0 : (row >= HH ? HH - 1 : row);
            const float* rp = plane + rrow * WW + gw;        // 16B aligned
            f32x4_t M = *(const f32x4_t*)rp;
            float vl = rp[l_edge ? 0 : -1];
            float vr = rp[r_edge ? 3 : 4];
            xd[r][0] = (valid && !l_edge) ? vl : 0.f;
            xd[r][1] = valid ? M.x : 0.f;
            xd[r][2] = valid ? M.y : 0.f;
            xd[r][3] = valid ? M.z : 0.f;
            xd[r][4] = valid ? M.w : 0.f;
            xd[r][5] = (valid && !r_edge) ? vr : 0.f;
        }
        // pin the burst: force all 60 values live in VGPRs here (anti-sink)
        #pragma unroll
        for (int r = 0; r < 10; ++r)
            #pragma unroll
            for (int t = 0; t < 6; ++t)
                asm volatile("" : "+v"(xd[r][t]));

        #pragma unroll
        for (int py = 0; py < 8; ++py) {
            #pragma unroll
            for (int i = 0; i < 4; ++i) {
                float sA = 0.f;
                #pragma unroll
                for (int t = 0; t < 3; ++t) {
                    sA = fmaf(xd[py + 0][i + t], kw[t],     sA);
                    sA = fmaf(xd[py + 1][i + t], kw[3 + t], sA);
                    sA = fmaf(xd[py + 2][i + t], kw[6 + t], sA);
                }
                __hip_bfloat16 hA = __float2bfloat16(sA);
                const int p = py * 8 + quad * 4 + i;          // p&7 = quad*4+i
                const unsigned boff = ((unsigned)(s << 1)) ^ (((unsigned)p & 7u) << 4);
                *reinterpret_cast<unsigned short*>(&xnb[(unsigned)p * 256 + boff]) =
                    *reinterpret_cast<unsigned short*>(&hA);
            }
        }
    }

    __syncthreads();

    // ---------------- stage 2: MFMA pointwise + BN + ReLU (R3-verified layout) ----------------
    {
        const int lane   = tid & 63;
        const int wv     = tid >> 6;       // 0..3
        const int lo     = lane & 15;
        const int hi     = lane >> 4;
        const int o_base = wv * 32;

        bf16x8_t afrag[2][4];
        #pragma unroll
        for (int t2 = 0; t2 < 2; ++t2)
            #pragma unroll
            for (int kc = 0; kc < 4; ++kc)
                afrag[t2][kc] = *reinterpret_cast<const bf16x8_t*>(
                    wper + (size_t)(o_base + t2 * 16 + lo) * CC + kc * 32 + hi * 8);

        f32x4_t acc[4][2];
        #pragma unroll
        for (int pt = 0; pt < 4; ++pt) {
            acc[pt][0] = (f32x4_t){0.f, 0.f, 0.f, 0.f};
            acc[pt][1] = (f32x4_t){0.f, 0.f, 0.f, 0.f};
        }

        #pragma unroll
        for (int pt = 0; pt < 4; ++pt) {
            const unsigned rowbase = (unsigned)(pt * 16 + lo) * 256;
            const unsigned sw = (unsigned)((lo & 7) << 4);
            #pragma unroll
            for (int kc = 0; kc < 4; ++kc) {
                bf16x8_t bfrag = *reinterpret_cast<const bf16x8_t*>(
                    &xnb[rowbase + (((unsigned)(kc * 64 + hi * 16)) ^ sw)]);
                acc[pt][0] = __builtin_amdgcn_mfma_f32_16x16x32_bf16(
                    afrag[0][kc], bfrag, acc[pt][0], 0, 0, 0);
                acc[pt][1] = __builtin_amdgcn_mfma_f32_16x16x32_bf16(
                    afrag[1][kc], bfrag, acc[pt][1], 0, 0, 0);
            }
        }

        f32x4_t iv[2], bs[2];
        #pragma unroll
        for (int t2 = 0; t2 < 2; ++t2) {
            iv[t2] = *reinterpret_cast<const f32x4_t*>(invp  + o_base + t2 * 16 + hi * 4);
            bs[t2] = *reinterpret_cast<const f32x4_t*>(biasp + o_base + t2 * 16 + hi * 4);
        }

        #pragma unroll
        for (int pt = 0; pt < 4; ++pt) {
            const int p  = pt * 16 + lo;
            const int py = p >> 3;
            const int px = p & 7;
            #pragma unroll
            for (int t2 = 0; t2 < 2; ++t2) {
                #pragma unroll
                for (int r = 0; r < 4; ++r) {
                    const int o = o_base + t2 * 16 + hi * 4 + r;
                    float val = fmaf(acc[pt][t2][r], iv[t2][r], bs[t2][r]);
                    val = fmaxf(val, 0.f);
                    out[((size_t)(bb * CC + o) * HH + (h0 + py)) * WW + w0 + px] = val;
                }
            }
        }
    }
}

extern "C" void kernel_launch(void* const* d_in, const int* in_sizes, int n_in,
                              void* d_out, int out_size, void* d_ws, size_t ws_size,
                              hipStream_t stream) {
    const float* x   = (const float*)d_in[0];
    const float* kk  = (const float*)d_in[1];
    const float* pwt = (const float*)d_in[2];
    const float* g   = (const float*)d_in[3];
    const float* b   = (const float*)d_in[4];
    const float* m   = (const float*)d_in[5];
    const float* v   = (const float*)d_in[6];
    float* out = (float*)d_out;

    unsigned short* wper = (unsigned short*)d_ws;                 // 32 KB
    float* inv  = (float*)((char*)d_ws + 32768);                  // 512 B
    float* bias = (float*)((char*)d_ws + 32768 + 512);            // 512 B

    prep_kernel<<<64, 256, 0, stream>>>(pwt, g, b, m, v, wper, inv, bias);
    fused_main<<<dim3(12 * 12 * BB), 256, 0, stream>>>(x, kk, wper, inv, bias, out);
}

// Round 7
// 130.079 us; speedup vs baseline: 1.1761x; 1.1761x over previous
//
#include <hip/hip_runtime.h>
#include <hip/hip_bf16.h>

#define BB 32
#define CC 128
#define HH 96
#define WW 96
#define BN_EPS 1e-5f

typedef __attribute__((ext_vector_type(8))) short bf16x8_t;
typedef __attribute__((ext_vector_type(4))) float f32x4_t;
typedef __attribute__((ext_vector_type(4), aligned(4))) float f32x4u_t;
typedef __attribute__((ext_vector_type(2))) unsigned int u32x2_t;
typedef __attribute__((ext_vector_type(4))) unsigned int u32x4_t;

// ---------------------------------------------------------------------------
// Prep: W fp32 -> bf16, k-permuted for mfma_f32_16x16x32_bf16 split-k frags
//   storage cidx = kc*32 + g*8 + j  <->  actual c = kc*32 + g*4 + (j&3) + 16*(j>>2)
// Also folds BN to inv/bias.   (unchanged — verified)
// ---------------------------------------------------------------------------
__global__ __launch_bounds__(256)
void prep_kernel(const float* __restrict__ pw,
                 const float* __restrict__ g, const float* __restrict__ b,
                 const float* __restrict__ m, const float* __restrict__ v,
                 unsigned short* __restrict__ wper,
                 float* __restrict__ inv, float* __restrict__ bias)
{
    int t = blockIdx.x * 256 + threadIdx.x;
    if (t < CC * CC) {
        int o = t >> 7, cidx = t & 127;
        int kc = cidx >> 5, r = cidx & 31, gg = r >> 3, j = r & 7;
        int c = kc * 32 + gg * 4 + (j & 3) + 16 * (j >> 2);
        __hip_bfloat16 h = __float2bfloat16(pw[o * CC + c]);
        wper[o * CC + cidx] = *reinterpret_cast<unsigned short*>(&h);
    }
    if (t < CC) {
        float iv = g[t] * rsqrtf(v[t] + BN_EPS);
        inv[t] = iv;
        bias[t] = b[t] - m[t] * iv;
    }
}

// ---------------------------------------------------------------------------
// Kernel A (R7): standalone streaming depthwise 3x3.
// Thread = (b, cs_storage, h, 8-wide w-oct): 12 independent VMEM, 72 FMA,
// one dwordx4 bf16 store to xn[b][cs][h][w]. ~60 VGPR -> 6 blocks/CU; TLP
// hides latency (no MFMA register pressure in this kernel — R4-R6 lesson).
// ---------------------------------------------------------------------------
__global__ __launch_bounds__(256, 6)
void dw_kernel(const float* __restrict__ x, const float* __restrict__ kk,
               unsigned short* __restrict__ xn)
{
    const int u = blockIdx.x * 256 + threadIdx.x;    // 32*128*96*12 units
    const int woct = u % 12;
    int t1 = u / 12;
    const int h = t1 % HH;
    int t2 = t1 / HH;
    const int cs = t2 & 127;
    const int b  = t2 >> 7;

    // storage -> actual channel permutation
    const int kc = cs >> 5, rr = cs & 31, gg = rr >> 3, jj = rr & 7;
    const int c = kc * 32 + gg * 4 + (jj & 3) + 16 * (jj >> 2);

    const int w0 = woct * 8;
    const bool l_edge = (w0 == 0);
    const bool r_edge = (w0 + 8 >= WW);

    const float* plane = x + (size_t)(b * CC + c) * (HH * WW);

    float kw[9];
    {
        const float* kp = kk + (size_t)(b * CC + c) * 9;
        f32x4u_t q0 = *(const f32x4u_t*)(kp);
        f32x4u_t q1 = *(const f32x4u_t*)(kp + 4);
        kw[0]=q0.x; kw[1]=q0.y; kw[2]=q0.z; kw[3]=q0.w;
        kw[4]=q1.x; kw[5]=q1.y; kw[6]=q1.z; kw[7]=q1.w;
        kw[8]=kp[8];
    }

    float xr[3][10];   // cols w0-1 .. w0+8 for rows h-1,h,h+1
    #pragma unroll
    for (int r = 0; r < 3; ++r) {
        const int row = h - 1 + r;
        const bool valid = (row >= 0) && (row < HH);
        const int rrow = row < 0 ? 0 : (row >= HH ? HH - 1 : row);
        const float* rp = plane + rrow * WW + w0;     // 32B aligned
        f32x4_t M0 = *(const f32x4_t*)rp;
        f32x4_t M1 = *(const f32x4_t*)(rp + 4);
        float vl = rp[l_edge ? 0 : -1];
        float vr = rp[r_edge ? 7 : 8];
        xr[r][0] = (valid && !l_edge) ? vl : 0.f;
        xr[r][1] = valid ? M0.x : 0.f;
        xr[r][2] = valid ? M0.y : 0.f;
        xr[r][3] = valid ? M0.z : 0.f;
        xr[r][4] = valid ? M0.w : 0.f;
        xr[r][5] = valid ? M1.x : 0.f;
        xr[r][6] = valid ? M1.y : 0.f;
        xr[r][7] = valid ? M1.z : 0.f;
        xr[r][8] = valid ? M1.w : 0.f;
        xr[r][9] = (valid && !r_edge) ? vr : 0.f;
    }

    u32x4_t pk;
    unsigned pkw[4];
    #pragma unroll
    for (int i = 0; i < 4; ++i) {
        float s0 = 0.f, s1 = 0.f;
        #pragma unroll
        for (int r = 0; r < 3; ++r) {
            #pragma unroll
            for (int t = 0; t < 3; ++t) {
                s0 = fmaf(xr[r][2 * i + t],     kw[r * 3 + t], s0);
                s1 = fmaf(xr[r][2 * i + 1 + t], kw[r * 3 + t], s1);
            }
        }
        __hip_bfloat16 h0b = __float2bfloat16(s0);
        __hip_bfloat16 h1b = __float2bfloat16(s1);
        pkw[i] = (unsigned)*reinterpret_cast<unsigned short*>(&h0b)
               | ((unsigned)*reinterpret_cast<unsigned short*>(&h1b) << 16);
    }
    pk.x = pkw[0]; pk.y = pkw[1]; pk.z = pkw[2]; pk.w = pkw[3];

    unsigned short* dst = xn + ((size_t)(b * CC + cs) * (HH * WW) + h * WW + w0);
    *reinterpret_cast<u32x4_t*>(dst) = pk;    // 16B aligned, coalesced
}

// ---------------------------------------------------------------------------
// Kernel B (R7): pointwise MFMA GEMM + BN + ReLU. One block = (b, 16w x 8h)
// tile. Staging: reg transpose (bf16x8 loads + v_perm pack + ds_write_b64)
// into the SAME XOR-swizzled LDS layout as R3 — stage-2 below is R3 verbatim.
// ---------------------------------------------------------------------------
__global__ __launch_bounds__(256, 3)
void pw_kernel(const unsigned short* __restrict__ xn,
               const unsigned short* __restrict__ wper,
               const float* __restrict__ invp, const float* __restrict__ biasp,
               float* __restrict__ out)
{
    __shared__ __align__(16) unsigned char xnb[128 * 256];
    const int tid = threadIdx.x;

    // chunked XCD swizzle (2304 = 8 x 288)
    const unsigned wg  = blockIdx.x;
    const unsigned nid = (wg & 7u) * 288u + (wg >> 3);
    const int tw = nid % 6u;
    const int th = (nid / 6u) % 12u;
    const int b  = nid / 72u;
    const int w0 = tw * 16;
    const int h0 = th * 8;

    // ---- staging with 4x8 register transpose ----
    {
        const int cs4 = tid >> 3;      // 0..31: 4-channel group
        const int py  = tid & 7;
        unsigned dL[4][4], dR[4][4];
        #pragma unroll
        for (int q = 0; q < 4; ++q) {
            const unsigned short* src = xn +
                ((size_t)(b * CC + cs4 * 4 + q) * (HH * WW) + (size_t)(h0 + py) * WW + w0);
            u32x4_t L = *(const u32x4_t*)src;        // px 0..7
            u32x4_t R = *(const u32x4_t*)(src + 8);  // px 8..15
            dL[q][0]=L.x; dL[q][1]=L.y; dL[q][2]=L.z; dL[q][3]=L.w;
            dR[q][0]=R.x; dR[q][1]=R.y; dR[q][2]=R.z; dR[q][3]=R.w;
        }
        #pragma unroll
        for (int o8 = 0; o8 < 2; ++o8) {
            #pragma unroll
            for (int j = 0; j < 4; ++j) {          // pixel pair 2j, 2j+1
                const unsigned d0 = o8 ? dR[0][j] : dL[0][j];
                const unsigned d1 = o8 ? dR[1][j] : dL[1][j];
                const unsigned d2 = o8 ? dR[2][j] : dL[2][j];
                const unsigned d3 = o8 ? dR[3][j] : dL[3][j];
                u32x2_t we, wo;
                we.x = __builtin_amdgcn_perm(d1, d0, 0x05040100u);  // ch0|ch1 (even px)
                we.y = __builtin_amdgcn_perm(d3, d2, 0x05040100u);  // ch2|ch3
                wo.x = __builtin_amdgcn_perm(d1, d0, 0x07060302u);  // odd px
                wo.y = __builtin_amdgcn_perm(d3, d2, 0x07060302u);
                const int pe = py * 16 + o8 * 8 + 2 * j;
                const int po = pe + 1;
                *reinterpret_cast<u32x2_t*>(&xnb[(unsigned)pe * 256 +
                    (((unsigned)cs4 * 8) ^ (((unsigned)pe & 7u) << 4))]) = we;
                *reinterpret_cast<u32x2_t*>(&xnb[(unsigned)po * 256 +
                    (((unsigned)cs4 * 8) ^ (((unsigned)po & 7u) << 4))]) = wo;
            }
        }
    }

    __syncthreads();

    // ---- stage 2: MFMA pointwise + BN + ReLU (R3-verified, verbatim) ----
    {
        const int lane   = tid & 63;
        const int wv     = tid >> 6;
        const int lo     = lane & 15;
        const int hi     = lane >> 4;
        const int o_base = wv * 32;

        bf16x8_t afrag[2][4];
        #pragma unroll
        for (int t2 = 0; t2 < 2; ++t2)
            #pragma unroll
            for (int kc = 0; kc < 4; ++kc)
                afrag[t2][kc] = *reinterpret_cast<const bf16x8_t*>(
                    wper + (size_t)(o_base + t2 * 16 + lo) * CC + kc * 32 + hi * 8);

        f32x4_t acc[8][2];
        #pragma unroll
        for (int pt = 0; pt < 8; ++pt) {
            acc[pt][0] = (f32x4_t){0.f, 0.f, 0.f, 0.f};
            acc[pt][1] = (f32x4_t){0.f, 0.f, 0.f, 0.f};
        }

        #pragma unroll
        for (int pt = 0; pt < 8; ++pt) {
            const unsigned rowbase = (unsigned)(pt * 16 + lo) * 256;
            const unsigned sw = (unsigned)((lo & 7) << 4);
            #pragma unroll
            for (int kc = 0; kc < 4; ++kc) {
                bf16x8_t bfrag = *reinterpret_cast<const bf16x8_t*>(
                    &xnb[rowbase + (((unsigned)(kc * 64 + hi * 16)) ^ sw)]);
                acc[pt][0] = __builtin_amdgcn_mfma_f32_16x16x32_bf16(
                    afrag[0][kc], bfrag, acc[pt][0], 0, 0, 0);
                acc[pt][1] = __builtin_amdgcn_mfma_f32_16x16x32_bf16(
                    afrag[1][kc], bfrag, acc[pt][1], 0, 0, 0);
            }
        }

        float iv[2][4], bs[2][4];
        #pragma unroll
        for (int t2 = 0; t2 < 2; ++t2)
            #pragma unroll
            for (int r = 0; r < 4; ++r) {
                const int o = o_base + t2 * 16 + hi * 4 + r;
                iv[t2][r] = invp[o];
                bs[t2][r] = biasp[o];
            }

        #pragma unroll
        for (int pt = 0; pt < 8; ++pt) {
            const int hrow = h0 + pt;
            #pragma unroll
            for (int t2 = 0; t2 < 2; ++t2) {
                #pragma unroll
                for (int r = 0; r < 4; ++r) {
                    const int o = o_base + t2 * 16 + hi * 4 + r;
                    float val = fmaf(acc[pt][t2][r], iv[t2][r], bs[t2][r]);
                    val = fmaxf(val, 0.f);
                    out[((size_t)(b * CC + o) * HH + hrow) * WW + w0 + lo] = val;
                }
            }
        }
    }
}

// ---------------------------------------------------------------------------
// Fallback (ws too small): R5 fused kernel, known-good at ~127 us e2e.
// ---------------------------------------------------------------------------
__global__ __launch_bounds__(256, 3)
void fused_main(const float* __restrict__ x, const float* __restrict__ kk,
                const unsigned short* __restrict__ wper,
                const float* __restrict__ invp, const float* __restrict__ biasp,
                float* __restrict__ out)
{
    __shared__ __align__(16) unsigned char xnb[128 * 256];
    const int tid = threadIdx.x;
    const unsigned wg  = blockIdx.x;
    const unsigned nid = (wg & 7u) * 288u + (wg >> 3);
    const int bx = nid % 6u;
    const int by = (nid / 6u) % 12u;
    const int bb = nid / 72u;
    const int w0 = bx * 16;
    const int h0 = by * 8;
    {
        const int wq = tid & 3;
        const int cp = tid >> 2;
        const int s  = cp << 1;
        const int kc = s >> 5, rr = s & 31, gg = rr >> 3, jj = rr & 7;
        const int cA = kc * 32 + gg * 4 + (jj & 3) + 16 * (jj >> 2);
        const int gw = w0 + wq * 4;
        const bool l_edge = (gw == 0);
        const bool r_edge = (gw + 4 >= WW);
        const float* planeA = x + (size_t)(bb * CC + cA) * (HH * WW);
        float kwA[9], kwB[9];
        {
            const float* kp = kk + (size_t)(bb * CC + cA) * 9;
            f32x4u_t q0 = *(const f32x4u_t*)(kp + 0);
            f32x4u_t q1 = *(const f32x4u_t*)(kp + 4);
            f32x4u_t q2 = *(const f32x4u_t*)(kp + 8);
            f32x4u_t q3 = *(const f32x4u_t*)(kp + 12);
            float     e16 = kp[16], e17 = kp[17];
            kwA[0]=q0.x; kwA[1]=q0.y; kwA[2]=q0.z; kwA[3]=q0.w;
            kwA[4]=q1.x; kwA[5]=q1.y; kwA[6]=q1.z; kwA[7]=q1.w;
            kwA[8]=q2.x;
            kwB[0]=q2.y; kwB[1]=q2.z; kwB[2]=q2.w;
            kwB[3]=q3.x; kwB[4]=q3.y; kwB[5]=q3.z; kwB[6]=q3.w;
            kwB[7]=e16;  kwB[8]=e17;
        }
        float xd[2][10][6];
        #pragma unroll
        for (int q = 0; q < 2; ++q) {
            const float* plane = planeA + q * (HH * WW);
            #pragma unroll
            for (int r = 0; r < 10; ++r) {
                const int row = h0 - 1 + r;
                const bool valid = (row >= 0) && (row < HH);
                const int rrow = row < 0 ? 0 : (row >= HH ? HH - 1 : row);
                const float* rp = plane + rrow * WW + gw;
                f32x4_t M = *(const f32x4_t*)rp;
                float vl = rp[l_edge ? 0 : -1];
                float vr = rp[r_edge ? 3 : 4];
                xd[q][r][0] = (valid && !l_edge) ? vl : 0.f;
                xd[q][r][1] = valid ? M.x : 0.f;
                xd[q][r][2] = valid ? M.y : 0.f;
                xd[q][r][3] = valid ? M.z : 0.f;
                xd[q][r][4] = valid ? M.w : 0.f;
                xd[q][r][5] = (valid && !r_edge) ? vr : 0.f;
            }
        }
        #pragma unroll
        for (int py = 0; py < 8; ++py) {
            #pragma unroll
            for (int i = 0; i < 4; ++i) {
                float sA = 0.f, sB = 0.f;
                #pragma unroll
                for (int t = 0; t < 3; ++t) {
                    sA = fmaf(xd[0][py + 0][i + t], kwA[t],     sA);
                    sA = fmaf(xd[0][py + 1][i + t], kwA[3 + t], sA);
                    sA = fmaf(xd[0][py + 2][i + t], kwA[6 + t], sA);
                    sB = fmaf(xd[1][py + 0][i + t], kwB[t],     sB);
                    sB = fmaf(xd[1][py + 1][i + t], kwB[3 + t], sB);
                    sB = fmaf(xd[1][py + 2][i + t], kwB[6 + t], sB);
                }
                __hip_bfloat16 hA = __float2bfloat16(sA);
                __hip_bfloat16 hB = __float2bfloat16(sB);
                unsigned pk = (unsigned)*reinterpret_cast<unsigned short*>(&hA)
                            | ((unsigned)*reinterpret_cast<unsigned short*>(&hB) << 16);
                const int p = py * 16 + wq * 4 + i;
                const unsigned boff = ((unsigned)(cp << 2)) ^ (((unsigned)p & 7u) << 4);
                *reinterpret_cast<unsigned*>(&xnb[(unsigned)p * 256 + boff]) = pk;
            }
        }
    }
    __syncthreads();
    {
        const int lane   = tid & 63;
        const int wv     = tid >> 6;
        const int lo     = lane & 15;
        const int hi     = lane >> 4;
        const int o_base = wv * 32;
        bf16x8_t afrag[2][4];
        #pragma unroll
        for (int t2 = 0; t2 < 2; ++t2)
            #pragma unroll
            for (int kc = 0; kc < 4; ++kc)
                afrag[t2][kc] = *reinterpret_cast<const bf16x8_t*>(
                    wper + (size_t)(o_base + t2 * 16 + lo) * CC + kc * 32 + hi * 8);
        f32x4_t acc[8][2];
        #pragma unroll
        for (int pt = 0; pt < 8; ++pt) {
            acc[pt][0] = (f32x4_t){0.f, 0.f, 0.f, 0.f};
            acc[pt][1] = (f32x4_t){0.f, 0.f, 0.f, 0.f};
        }
        #pragma unroll
        for (int pt = 0; pt < 8; ++pt) {
            const unsigned rowbase = (unsigned)(pt * 16 + lo) * 256;
            const unsigned sw = (unsigned)((lo & 7) << 4);
            #pragma unroll
            for (int kc = 0; kc < 4; ++kc) {
                bf16x8_t bfrag = *reinterpret_cast<const bf16x8_t*>(
                    &xnb[rowbase + (((unsigned)(kc * 64 + hi * 16)) ^ sw)]);
                acc[pt][0] = __builtin_amdgcn_mfma_f32_16x16x32_bf16(
                    afrag[0][kc], bfrag, acc[pt][0], 0, 0, 0);
                acc[pt][1] = __builtin_amdgcn_mfma_f32_16x16x32_bf16(
                    afrag[1][kc], bfrag, acc[pt][1], 0, 0, 0);
            }
        }
        float iv[2][4], bs[2][4];
        #pragma unroll
        for (int t2 = 0; t2 < 2; ++t2)
            #pragma unroll
            for (int r = 0; r < 4; ++r) {
                const int o = o_base + t2 * 16 + hi * 4 + r;
                iv[t2][r] = invp[o];
                bs[t2][r] = biasp[o];
            }
        #pragma unroll
        for (int pt = 0; pt < 8; ++pt) {
            const int hrow = h0 + pt;
            #pragma unroll
            for (int t2 = 0; t2 < 2; ++t2) {
                #pragma unroll
                for (int r = 0; r < 4; ++r) {
                    const int o = o_base + t2 * 16 + hi * 4 + r;
                    float val = fmaf(acc[pt][t2][r], iv[t2][r], bs[t2][r]);
                    val = fmaxf(val, 0.f);
                    out[((size_t)(bb * CC + o) * HH + hrow) * WW + w0 + lo] = val;
                }
            }
        }
    }
}

extern "C" void kernel_launch(void* const* d_in, const int* in_sizes, int n_in,
                              void* d_out, int out_size, void* d_ws, size_t ws_size,
                              hipStream_t stream) {
    const float* x   = (const float*)d_in[0];
    const float* kk  = (const float*)d_in[1];
    const float* pwt = (const float*)d_in[2];
    const float* g   = (const float*)d_in[3];
    const float* b   = (const float*)d_in[4];
    const float* m   = (const float*)d_in[5];
    const float* v   = (const float*)d_in[6];
    float* out = (float*)d_out;

    unsigned short* wper = (unsigned short*)d_ws;                 // 32 KB
    float* inv  = (float*)((char*)d_ws + 32768);                  // 512 B
    float* bias = (float*)((char*)d_ws + 32768 + 512);            // 512 B
    unsigned short* xn = (unsigned short*)((char*)d_ws + 36864);  // 75.5 MB
    const size_t need = 36864 + (size_t)BB * CC * HH * WW * 2;

    prep_kernel<<<64, 256, 0, stream>>>(pwt, g, b, m, v, wper, inv, bias);
    if (ws_size >= need) {
        dw_kernel<<<dim3(18432), 256, 0, stream>>>(x, kk, xn);
        pw_kernel<<<dim3(2304), 256, 0, stream>>>(xn, wper, inv, bias, out);
    } else {
        fused_main<<<dim3(2304), 256, 0, stream>>>(x, kk, wper, inv, bias, out);
    }
}